// Round 10
// baseline (153.758 us; speedup 1.0000x reference)
//
#include <hip/hip_runtime.h>
#include <math.h>

#define IMG_H 512
#define IMG_W 512
#define NPLANES 48            // 16 * 3
#define RAD 5
#define TAPS 11
#define CHUNK 33              // multiple of 11 -> static ring phase after unroll
#define STRIP 64              // columns per wave (one autonomous wave per strip)
#define SBUF 80               // 74 used (64 + 2*RAD), padded

typedef float v2f __attribute__((ext_vector_type(2)));

// Compiler-only fence: cross-lane LDS dependence (lane i reads what lane j
// wrote) is INVISIBLE to LLVM alias analysis — an early round failed
// correctness exactly this way. HW needs nothing: wave has one PC and
// same-wave DS ops complete in order.
#define WAVE_FENCE_WAR()  __asm__ __volatile__("" ::: "memory")
#define WAVE_FENCE_RAW()  __asm__ __volatile__("s_waitcnt lgkmcnt(0)" ::: "memory")

struct GaussW { float w[TAPS]; };

// Structure notes (evidence-driven). Ledger:
//  - Busy-cycle INVARIANT: VALUBusy x dur ~= 47us-eq for every non-spilled
//    variant (R0/R12/R15). VALU work is fixed; only stall varies. The stall
//    is residency-round quantization: 1536 blocks at 4 blocks/CU cap = 1024
//    co-resident -> round 2 runs 512 blocks on 1024 slots -> 75% slot util
//    x ~90% in-block busy = measured 67% VALUBusy. In-loop surgery (R15
//    reorder/fences/prefetch-2: 85us) cannot touch this.
//  - R16 (this): make all 6 blocks/CU co-resident. Footprint 104 -> ~82
//    regs (<= 512/6 = 85) via (a) rsq ring 2-wide -> rq 1-wide: SSIM only
//    needs sg1+sg2 and mu1^2+mu2^2, so store conv_h(a^2+b^2) scalar
//    (-11 regs, +1 add/row); (b) rx ring -> LDS [4][11][64] (-11 regs,
//    +1 ds_write +11 ds_read_b32/row-step, same-lane deps, conflict-free,
//    LDS pipe 25->37 clk vs ~430 VALU clk). Then (256,6) is legal: R2's
//    (256,6) spill was footprint 104 > cap 85 — cause removed.
//  - R2/R7: reg cap below footprint spills the ring (WRITE_SIZE 48KB ->
//    200+MB, 70 -> 219+us). WRITE_SIZE is the tripwire for THIS round too.
//  - R8/R9: full straight-line unroll of the row loop -> spill. Keep the
//    `for kk` + 11-row `#pragma unroll` body EXACTLY.
//  - R14: float4 staging doubled LDS read bytes/tap -> LDS-bound regression.
//    Staging stays (a,b) float2.
//  - R10..R13: finalize-fold arc dead (fixed ~83us graph overhead
//    regardless of dispatch count; folded tail cost ~38us in-kernel).
//  - R3: per-row block barriers lockstep. R5: one wave per 64-col strip.
//    R6: packed fp32 (v_pk_fma).
__global__ __launch_bounds__(256, 6)
void ssim_main(const float* __restrict__ img1, const float* __restrict__ img2,
               double* __restrict__ sum_ws, GaussW gw) {
    __shared__ float2 srow[4][SBUF];       // one private (a,b) row buffer per wave
    __shared__ float  srx[4][TAPS][64];    // rx ring, one [11][64] per wave
    __shared__ float  wsum[4];

    const int tid  = threadIdx.x;
    const int wid  = tid >> 6;         // wave id 0..3
    const int lane = tid & 63;
    const int c0   = blockIdx.x * (4 * STRIP) + wid * STRIP;  // strip base col
    const int y0   = blockIdx.y * CHUNK;
    const size_t pbase = (size_t)blockIdx.z * (IMG_H * IMG_W);
    const float* p1 = img1 + pbase;
    const float* p2 = img2 + pbase;
    float2* buf  = srow[wid];
    float*  bufx = &srx[wid][0][0];

    // register rings, 11 rows deep (rx ring lives in LDS now):
    //   rab = (conv_h(a), conv_h(b))      packed, 2-wide
    //   rq  = conv_h(a^2) + conv_h(b^2)   scalar, 1-wide (SSIM only needs sum)
    v2f rab[TAPS];
    float rq[TAPS];

    // prefetch registers for the next row (main col + 10-col tail)
    float pa, pb, pta, ptb;

    auto load_regs = [&](int r) {
        pa = pb = pta = ptb = 0.f;
        if (r >= 0 && r < IMG_H) {     // wave-uniform
            const float* row1 = p1 + (size_t)r * IMG_W;
            const float* row2 = p2 + (size_t)r * IMG_W;
            int col = c0 - RAD + lane;              // buf idx = lane
            if (col >= 0 && col < IMG_W) { pa = row1[col]; pb = row2[col]; }
            if (lane < 2 * RAD) {                   // buf idx = 64+lane
                int c2 = c0 + STRIP - RAD + lane;   // cols c0+59..c0+68
                if (c2 < IMG_W) { pta = row1[c2]; ptb = row2[c2]; }
            }
        }
    };

    auto store_lds = [&]() {
        WAVE_FENCE_WAR();              // don't sink this write above prior reads
        buf[lane] = make_float2(pa, pb);
        if (lane < 2 * RAD) buf[STRIP + lane] = make_float2(pta, ptb);
        WAVE_FENCE_RAW();              // don't hoist following reads above it
    };

    // packed horizontal conv: per tap 1 pk_mul + 1 mul + 2 pk_fma + 1 fma;
    // collapse the packed square accumulator once per row; rx -> LDS slot.
    auto hconv = [&](int r, int slot, v2f& oab, float& orq) {
        v2f aab = {0.f, 0.f}, asq = {0.f, 0.f};
        float ax = 0.f;
        if (r >= 0 && r < IMG_H) {     // wave-uniform: padded rows contribute zero
            #pragma unroll
            for (int d = 0; d < TAPS; ++d) {
                v2f v = *(const v2f*)&buf[lane + d];   // (a, b)
                float w = gw.w[d];
                v2f wv = {w, w};
                aab = __builtin_elementwise_fma(wv, v, aab);          // pk_fma
                v2f sq = v * v;                                       // pk_mul
                asq = __builtin_elementwise_fma(wv, sq, asq);         // pk_fma
                ax  = fmaf(w, v.x * v.y, ax);                         // mul+fma
            }
        }
        oab = aab;
        orq = asq.x + asq.y;           // conv_h(a^2)+conv_h(b^2), 1-wide
        bufx[slot * 64 + lane] = ax;   // rx ring slot in LDS (same-lane dep)
    };

    // ---- prologue: h-rows 0..9 (global rows y0-5 .. y0+4) -> ring slots 0..9
    load_regs(y0 - RAD);
    #pragma unroll
    for (int k = 0; k < TAPS - 1; ++k) {
        const int r = y0 - RAD + k;
        store_lds();
        load_regs(r + 1);              // next row's loads in flight during hconv
        hconv(r, k, rab[k], rq[k]);
    }

    const float C1v = 0.0001f;  // 0.01^2
    const float C2v = 0.0009f;  // 0.03^2
    float acc = 0.f;

    // ---- main: CHUNK output rows, unrolled by 11 so ring indices are static
    for (int kk = 0; kk < CHUNK; kk += TAPS) {
        #pragma unroll
        for (int j = 0; j < TAPS; ++j) {
            const int r = y0 - RAD + (TAPS - 1) + kk + j;  // global input row
            store_lds();               // publish prefetched row r
            load_regs(r + 1);          // issue loads for row r+1 NOW
            hconv(r, (j + 10) % TAPS, rab[(j + 10) % TAPS], rq[(j + 10) % TAPS]);

            const int y = y0 + kk + j; // output row
            if (y < IMG_H) {
                // vertical conv: per tap 1 pk_fma (mu) + 1 fma (q) + 1 fma (x)
                v2f mu = {0.f, 0.f};
                float s2q = 0.f, sx = 0.f;
                #pragma unroll
                for (int t = 0; t < TAPS; ++t) {
                    const int s = (j + t) % TAPS;  // static after unroll
                    float w = gw.w[t];
                    v2f wv = {w, w};
                    mu  = __builtin_elementwise_fma(wv, rab[s], mu);
                    s2q = fmaf(w, rq[s], s2q);
                    sx  = fmaf(w, bufx[s * 64 + lane], sx);  // rx from LDS
                }
                float mu1 = mu.x, mu2 = mu.y;
                float mu1sq = mu1 * mu1, mu2sq = mu2 * mu2, mu12 = mu1 * mu2;
                float musq = mu1sq + mu2sq;
                float sgs  = s2q - musq;        // sigma1^2 + sigma2^2
                float sg12 = sx - mu12;
                float num = (2.f * mu12 + C1v) * (2.f * sg12 + C2v);
                float den = (musq + C1v) * (sgs + C2v);
                acc += num * __builtin_amdgcn_rcpf(den);
            }
        }
    }

    // wave (64-lane) shuffle reduce -> block partials -> one atomic per block
    #pragma unroll
    for (int off = 32; off > 0; off >>= 1) acc += __shfl_down(acc, off, 64);
    if (lane == 0) wsum[wid] = acc;
    __syncthreads();                   // only block barrier in the kernel
    if (tid == 0) {
        double s = (double)wsum[0] + (double)wsum[1] + (double)wsum[2] + (double)wsum[3];
        atomicAdd(sum_ws, s);
    }
}

__global__ void ssim_finalize(const double* __restrict__ sum_ws, float* __restrict__ out) {
    out[0] = (float)(sum_ws[0] * (1.0 / (double)(16.0 * 3.0 * 512.0 * 512.0)));
}

extern "C" void kernel_launch(void* const* d_in, const int* in_sizes, int n_in,
                              void* d_out, int out_size, void* d_ws, size_t ws_size,
                              hipStream_t stream) {
    const float* img1 = (const float*)d_in[0];
    const float* img2 = (const float*)d_in[1];
    float* out = (float*)d_out;
    double* ws = (double*)d_ws;

    // d_ws is poisoned 0xAA before every launch — zero the accumulator (async, capture-safe)
    hipMemsetAsync(ws, 0, sizeof(double), stream);

    // Gaussian weights computed on host in double, passed via kernarg (SGPRs)
    GaussW gw;
    double g[TAPS], s = 0.0;
    for (int i = 0; i < TAPS; ++i) {
        double x = (double)(i - TAPS / 2);
        g[i] = exp(-(x * x) / (2.0 * 1.5 * 1.5));
        s += g[i];
    }
    for (int i = 0; i < TAPS; ++i) gw.w[i] = (float)(g[i] / s);

    // 2 x 16 x 48 = 1536 blocks = 6 per CU, now ALL co-resident (one
    // residency round); each block = 4 autonomous 64-col wave strips
    dim3 grid(IMG_W / (4 * STRIP), (IMG_H + CHUNK - 1) / CHUNK, NPLANES);
    ssim_main<<<grid, 256, 0, stream>>>(img1, img2, ws, gw);
    ssim_finalize<<<1, 1, 0, stream>>>(ws, out);
}